// Round 6
// baseline (367.745 us; speedup 1.0000x reference)
//
#include <hip/hip_runtime.h>
#include <hip/hip_bf16.h>
#include <math.h>

// Problem constants (fixed by setup_inputs): N=2048, D=512, K=65536
#define N_ROWS 2048
#define D_DIM  512
#define K_NEG  65536
#define INV_T  5.0f   // 1/0.2
#define LOG2E  1.44269504f
#define NC     4      // colBlocks processed per block (epilogue amortization)
#define NT     (NC * 8)    // flat pipeline iterations: NC colBlocks x 8 kt (K=64 each)

typedef int i32x4 __attribute__((ext_vector_type(4)));

__device__ __forceinline__ void gload_lds16(const char* g, char* l) {
    __builtin_amdgcn_global_load_lds(
        (const __attribute__((address_space(1))) void*)g,
        (__attribute__((address_space(3))) void*)l, 16, 0, 0);
}

// i8 MFMA via inline asm (ISA §10).  "+v" ties C and D -> in-place accumulate.
__device__ __forceinline__ void mfma_i8(i32x4& c, i32x4 a, i32x4 b) {
    asm volatile("v_mfma_i32_16x16x64_i8 %0, %1, %2, %0"
                 : "+v"(c) : "v"(a), "v"(b));
}

// quantize 4 floats by qm, round-nearest, pack to one i32 (byte0=x0..byte3=x3)
__device__ __forceinline__ int pack4(float x0, float x1, float x2, float x3, float qm) {
    const int a = (int)rintf(x0 * qm), b = (int)rintf(x1 * qm);
    const int c = (int)rintf(x2 * qm), d = (int)rintf(x3 * qm);
    return (a & 255) | ((b & 255) << 8) | ((c & 255) << 16) | (d << 24);
}

// ---------------------------------------------------------------------------
// Kernel 1 (merged preps): per-row symmetric i8 + scales.
// fA is pre-scaled by LOG2E so the gemm epilogue uses hardware exp2 directly.
//  blocks [0, 256):     q/k rows; 2 rows/wave.  fp32-exact lpos/qn/kn.
//  blocks [256, 2304):  queue rows; 8 rows/wave. Bi8 + fB = step/un.
// ---------------------------------------------------------------------------
__global__ __launch_bounds__(256) void prep_all_kernel(
    const float* __restrict__ query, const float* __restrict__ keys,
    const float* __restrict__ queue,
    char* __restrict__ Ai8, char* __restrict__ Bi8,
    float* __restrict__ fA, float* __restrict__ fB,
    float* __restrict__ lpos, float* __restrict__ rowsum) {
    const int wave = threadIdx.x >> 6;
    const int lane = threadIdx.x & 63;
    if (blockIdx.x < 256) {
#pragma unroll
        for (int rr = 0; rr < 2; ++rr) {
            const int row = (blockIdx.x << 3) + (wave << 1) + rr;
            const float4* qv = reinterpret_cast<const float4*>(query + (size_t)row * D_DIM) + lane * 2;
            const float4* kv = reinterpret_cast<const float4*>(keys  + (size_t)row * D_DIM) + lane * 2;
            float4 q0 = qv[0], q1 = qv[1];
            float4 k0 = kv[0], k1 = kv[1];
            float ssq = q0.x*q0.x + q0.y*q0.y + q0.z*q0.z + q0.w*q0.w
                      + q1.x*q1.x + q1.y*q1.y + q1.z*q1.z + q1.w*q1.w;
            float ssk = k0.x*k0.x + k0.y*k0.y + k0.z*k0.z + k0.w*k0.w
                      + k1.x*k1.x + k1.y*k1.y + k1.z*k1.z + k1.w*k1.w;
            float dot = q0.x*k0.x + q0.y*k0.y + q0.z*k0.z + q0.w*k0.w
                      + q1.x*k1.x + q1.y*k1.y + q1.z*k1.z + q1.w*k1.w;
            float amx = fmaxf(fmaxf(fmaxf(fabsf(q0.x), fabsf(q0.y)),
                                    fmaxf(fabsf(q0.z), fabsf(q0.w))),
                              fmaxf(fmaxf(fabsf(q1.x), fabsf(q1.y)),
                                    fmaxf(fabsf(q1.z), fabsf(q1.w))));
#pragma unroll
            for (int off = 32; off > 0; off >>= 1) {
                ssq += __shfl_xor(ssq, off, 64);
                ssk += __shfl_xor(ssk, off, 64);
                dot += __shfl_xor(dot, off, 64);
                amx = fmaxf(amx, __shfl_xor(amx, off, 64));
            }
            const float qm = 127.0f / amx;
            const int p0 = pack4(q0.x, q0.y, q0.z, q0.w, qm);
            const int p1 = pack4(q1.x, q1.y, q1.z, q1.w, qm);
            reinterpret_cast<int2*>(Ai8 + (size_t)row * D_DIM)[lane] = make_int2(p0, p1);
            if (lane == 0) {
                float qn = sqrtf(ssq), kn = sqrtf(ssk);
                float lp = dot / fmaxf(qn * kn, 1e-8f) * INV_T;
                fA[row]     = amx * (INV_T * LOG2E / 127.0f) / fmaxf(qn, 1e-8f);
                lpos[row]   = lp;
                rowsum[row] = __expf(lp);   // positive-logit term; inits accumulator
            }
        }
    } else {
        const int qb = blockIdx.x - 256;
#pragma unroll
        for (int rr = 0; rr < 8; ++rr) {
            const int row = (qb << 5) + (wave << 3) + rr;
            const float4* uv = reinterpret_cast<const float4*>(queue + (size_t)row * D_DIM) + lane * 2;
            float4 u0 = uv[0], u1 = uv[1];
            float ss = u0.x*u0.x + u0.y*u0.y + u0.z*u0.z + u0.w*u0.w
                     + u1.x*u1.x + u1.y*u1.y + u1.z*u1.z + u1.w*u1.w;
            float amx = fmaxf(fmaxf(fmaxf(fabsf(u0.x), fabsf(u0.y)),
                                    fmaxf(fabsf(u0.z), fabsf(u0.w))),
                              fmaxf(fmaxf(fabsf(u1.x), fabsf(u1.y)),
                                    fmaxf(fabsf(u1.z), fabsf(u1.w))));
#pragma unroll
            for (int off = 32; off > 0; off >>= 1) {
                ss  += __shfl_xor(ss, off, 64);
                amx = fmaxf(amx, __shfl_xor(amx, off, 64));
            }
            const float qm = 127.0f / amx;
            const int p0 = pack4(u0.x, u0.y, u0.z, u0.w, qm);
            const int p1 = pack4(u1.x, u1.y, u1.z, u1.w, qm);
            reinterpret_cast<int2*>(Bi8 + (size_t)row * D_DIM)[lane] = make_int2(p0, p1);
            if (lane == 0)
                fB[row] = amx * (1.0f / 127.0f) / fmaxf(sqrtf(ss), 1e-8f);
        }
    }
}

// ---------------------------------------------------------------------------
// Kernel 2: NT-GEMM (i8, K=64/instr) with fused exp-rowsum.
// Round-6: register-slimmed round-3 loop + __launch_bounds__(256, 4).
// Round-5 showed (256,4) on the fat loop SPILLS (WRITE_SIZE 8->141 MB,
// gemm 114->166us) even though occupancy rose 29->42%.  The occupancy
// mechanism is untested, not refuted -> slim the live set ~28 regs:
//   (1) bq loaded one-at-a-time in a j-outer loop (16 -> 4 regs live);
//   (2) srow[4][4] and fAv[4][4] eliminated: shuffle-reduce + atomicAdd
//       moved into the per-colBlock epilogue, fA loaded there (transient).
// Live set ~= acc 64 + af 16 + bq 4 + addressing ~16 + misc ~12 ~= 112 < 128.
// Loop structure otherwise IDENTICAL to round-3 (2 LDS buffers, plain
// __syncthreads, depth-1 prefetch — depth-2/counted-vmcnt refuted round 4).
// Spill tripwire: WRITE_SIZE must stay ~8 MB.
// ---------------------------------------------------------------------------
__global__ __launch_bounds__(256, 4) void gemm_exp_kernel(
    const char* __restrict__ A, const char* __restrict__ B,
    const float* __restrict__ fA, const float* __restrict__ fB,
    float* __restrict__ rowsum) {
    __shared__ char sA[2 * 8192];
    __shared__ char sB[2 * 8192];
    const int tid  = threadIdx.x;
    const int wave = tid >> 6, lane = tid & 63;
    const int rowBlock = blockIdx.x;   // 0..15  (fastest -> B-tile temporal locality)
    const int colGroup = blockIdx.y;   // 0..127 (NC=4 colBlocks each)

    const int wm = wave >> 1, wn = wave & 1;
    const int q4 = lane >> 4, m16 = lane & 15;

    // staging lane map: lane = r4*4 + c2; LDS slot (r4,c2) <- global chunk
    // g = c2 ^ ((r4>>1)&3)  (source-address swizzle; dest is uniform+lane*16)
    const int r4 = lane >> 2, c2 = lane & 3;
    const int gsw = c2 ^ ((r4 >> 1) & 3);
    const int j0 = wave, j1 = wave + 4;          // 16-row chunks this wave stages
    const char* gA  = A + ((size_t)(rowBlock * 128 + r4)) * 512 + gsw * 16;
    const char* gB0 = B + ((size_t)(colGroup * NC * 128 + r4)) * 512 + gsw * 16;
    const int rsw = (q4 ^ ((m16 >> 1) & 3)) * 16;   // read-side swizzled byte offset

    i32x4 acc[4][4] = {};

    // stage(t, bufsel): issue 4 global_load_lds for iteration t
#define STAGE(T, BUF) do {                                                        \
        const int cb_ = (T) >> 3, kof_ = ((T) & 7) * 64;                          \
        const char* gBc_ = gB0 + ((size_t)cb_ << 16);                             \
        char* dA_ = &sA[(BUF) * 8192];                                            \
        char* dB_ = &sB[(BUF) * 8192];                                            \
        gload_lds16(gA   + (size_t)j0 * 16 * 512 + kof_, &dA_[j0 * 1024]);        \
        gload_lds16(gA   + (size_t)j1 * 16 * 512 + kof_, &dA_[j1 * 1024]);        \
        gload_lds16(gBc_ + (size_t)j0 * 16 * 512 + kof_, &dB_[j0 * 1024]);        \
        gload_lds16(gBc_ + (size_t)j1 * 16 * 512 + kof_, &dB_[j1 * 1024]);        \
    } while (0)

    STAGE(0, 0);

    for (int t = 0; t < NT; ++t) {
        const int cur = t & 1;
        __syncthreads();                  // drains loads(t) (one stage in flight)
        if (t + 1 < NT) STAGE(t + 1, cur ^ 1);

        const char* bA = &sA[cur * 8192];
        const char* bB = &sB[cur * 8192];
        i32x4 af[4];
#pragma unroll
        for (int i = 0; i < 4; ++i)
            af[i] = *reinterpret_cast<const i32x4*>(&bA[(wm * 64 + i * 16 + m16) * 64 + rsw]);
#pragma unroll
        for (int j = 0; j < 4; ++j) {     // bq one-at-a-time: 4 regs live, not 16
            const i32x4 bq = *reinterpret_cast<const i32x4*>(&bB[(wn * 64 + j * 16 + m16) * 64 + rsw]);
#pragma unroll
            for (int i = 0; i < 4; ++i)
                mfma_i8(acc[i][j], af[i], bq);
        }

        if ((t & 7) == 7) {               // colBlock done: exp, reduce, atomic, reset
            const int colBlock = colGroup * NC + (t >> 3);
            float fBv[4];
#pragma unroll
            for (int j = 0; j < 4; ++j)
                fBv[j] = fB[colBlock * 128 + wn * 64 + j * 16 + m16];
#pragma unroll
            for (int i = 0; i < 4; ++i)
#pragma unroll
                for (int r = 0; r < 4; ++r) {
                    const int grow = rowBlock * 128 + wm * 64 + i * 16 + q4 * 4 + r;
                    const float fa = fA[grow];
                    float s = 0.f;
#pragma unroll
                    for (int j = 0; j < 4; ++j)
                        s += __builtin_exp2f((float)acc[i][j][r] * fa * fBv[j]);
#pragma unroll
                    for (int off = 1; off < 16; off <<= 1)
                        s += __shfl_xor(s, off, 64);
                    if (m16 == 0) atomicAdd(&rowsum[grow], s);
                    acc[i][0][r] = 0; acc[i][1][r] = 0;
                    acc[i][2][r] = 0; acc[i][3][r] = 0;
                }
        }
    }
#undef STAGE
}

// ---------------------------------------------------------------------------
// Kernel 3: loss = mean(log(rowsum) - lpos)
// ---------------------------------------------------------------------------
__global__ __launch_bounds__(256) void finalize_kernel(
    const float* __restrict__ rowsum, const float* __restrict__ lpos,
    float* __restrict__ out) {
    const int tid = threadIdx.x;
    float acc = 0.f;
    for (int n = tid; n < N_ROWS; n += 256)
        acc += __logf(rowsum[n]) - lpos[n];
#pragma unroll
    for (int off = 32; off > 0; off >>= 1) acc += __shfl_xor(acc, off, 64);
    __shared__ float red[4];
    if ((tid & 63) == 0) red[tid >> 6] = acc;
    __syncthreads();
    if (tid == 0) out[0] = (red[0] + red[1] + red[2] + red[3]) * (1.0f / (float)N_ROWS);
}

extern "C" void kernel_launch(void* const* d_in, const int* in_sizes, int n_in,
                              void* d_out, int out_size, void* d_ws, size_t ws_size,
                              hipStream_t stream) {
    const float* query = (const float*)d_in[0];
    const float* keys  = (const float*)d_in[1];
    const float* queue = (const float*)d_in[2];

    char* ws = (char*)d_ws;
    char*  Ai8 = ws;            ws += (size_t)N_ROWS * D_DIM;                 // 1 MB
    char*  Bi8 = ws;            ws += (size_t)K_NEG  * D_DIM;                 // 32 MB
    float* fA   = (float*)ws;   ws += (size_t)N_ROWS * sizeof(float);
    float* fB   = (float*)ws;   ws += (size_t)K_NEG  * sizeof(float);
    float* lpos = (float*)ws;   ws += (size_t)N_ROWS * sizeof(float);
    float* rsum = (float*)ws;   ws += (size_t)N_ROWS * sizeof(float);

    prep_all_kernel<<<2304, 256, 0, stream>>>(
        query, keys, queue, Ai8, Bi8, fA, fB, lpos, rsum);
    gemm_exp_kernel<<<dim3(N_ROWS / 128, K_NEG / 128 / NC), 256, 0, stream>>>(
        Ai8, Bi8, fA, fB, rsum);
    finalize_kernel<<<1, 256, 0, stream>>>(rsum, lpos, (float*)d_out);
}

// Round 7
// 317.151 us; speedup vs baseline: 1.1595x; 1.1595x over previous
//
#include <hip/hip_runtime.h>
#include <hip/hip_bf16.h>
#include <math.h>

// Problem constants (fixed by setup_inputs): N=2048, D=512, K=65536
#define N_ROWS 2048
#define D_DIM  512
#define K_NEG  65536
#define INV_T  5.0f   // 1/0.2
#define LOG2E  1.44269504f
#define NC     4      // colBlocks processed per block (epilogue amortization)
#define NT     (NC * 8)    // flat pipeline iterations: NC colBlocks x 8 kt (K=64 each)

typedef int i32x4 __attribute__((ext_vector_type(4)));

__device__ __forceinline__ void gload_lds16(const char* g, char* l) {
    __builtin_amdgcn_global_load_lds(
        (const __attribute__((address_space(1))) void*)g,
        (__attribute__((address_space(3))) void*)l, 16, 0, 0);
}

// i8 MFMA via inline asm (ISA §10).  "+v" ties C and D -> in-place accumulate.
__device__ __forceinline__ void mfma_i8(i32x4& c, i32x4 a, i32x4 b) {
    asm volatile("v_mfma_i32_16x16x64_i8 %0, %1, %2, %0"
                 : "+v"(c) : "v"(a), "v"(b));
}

// quantize 4 floats by qm, round-nearest, pack to one i32 (byte0=x0..byte3=x3)
__device__ __forceinline__ int pack4(float x0, float x1, float x2, float x3, float qm) {
    const int a = (int)rintf(x0 * qm), b = (int)rintf(x1 * qm);
    const int c = (int)rintf(x2 * qm), d = (int)rintf(x3 * qm);
    return (a & 255) | ((b & 255) << 8) | ((c & 255) << 16) | (d << 24);
}

// ---------------------------------------------------------------------------
// Kernel 1 (merged preps): per-row symmetric i8 + scales.
// fA is pre-scaled by LOG2E so the gemm epilogue uses hardware exp2 directly.
//  blocks [0, 256):     q/k rows; 2 rows/wave.  fp32-exact lpos/qn/kn.
//  blocks [256, 2304):  queue rows; 8 rows/wave. Bi8 + fB = step/un.
// ---------------------------------------------------------------------------
__global__ __launch_bounds__(256) void prep_all_kernel(
    const float* __restrict__ query, const float* __restrict__ keys,
    const float* __restrict__ queue,
    char* __restrict__ Ai8, char* __restrict__ Bi8,
    float* __restrict__ fA, float* __restrict__ fB,
    float* __restrict__ lpos, float* __restrict__ rowsum) {
    const int wave = threadIdx.x >> 6;
    const int lane = threadIdx.x & 63;
    if (blockIdx.x < 256) {
#pragma unroll
        for (int rr = 0; rr < 2; ++rr) {
            const int row = (blockIdx.x << 3) + (wave << 1) + rr;
            const float4* qv = reinterpret_cast<const float4*>(query + (size_t)row * D_DIM) + lane * 2;
            const float4* kv = reinterpret_cast<const float4*>(keys  + (size_t)row * D_DIM) + lane * 2;
            float4 q0 = qv[0], q1 = qv[1];
            float4 k0 = kv[0], k1 = kv[1];
            float ssq = q0.x*q0.x + q0.y*q0.y + q0.z*q0.z + q0.w*q0.w
                      + q1.x*q1.x + q1.y*q1.y + q1.z*q1.z + q1.w*q1.w;
            float ssk = k0.x*k0.x + k0.y*k0.y + k0.z*k0.z + k0.w*k0.w
                      + k1.x*k1.x + k1.y*k1.y + k1.z*k1.z + k1.w*k1.w;
            float dot = q0.x*k0.x + q0.y*k0.y + q0.z*k0.z + q0.w*k0.w
                      + q1.x*k1.x + q1.y*k1.y + q1.z*k1.z + q1.w*k1.w;
            float amx = fmaxf(fmaxf(fmaxf(fabsf(q0.x), fabsf(q0.y)),
                                    fmaxf(fabsf(q0.z), fabsf(q0.w))),
                              fmaxf(fmaxf(fabsf(q1.x), fabsf(q1.y)),
                                    fmaxf(fabsf(q1.z), fabsf(q1.w))));
#pragma unroll
            for (int off = 32; off > 0; off >>= 1) {
                ssq += __shfl_xor(ssq, off, 64);
                ssk += __shfl_xor(ssk, off, 64);
                dot += __shfl_xor(dot, off, 64);
                amx = fmaxf(amx, __shfl_xor(amx, off, 64));
            }
            const float qm = 127.0f / amx;
            const int p0 = pack4(q0.x, q0.y, q0.z, q0.w, qm);
            const int p1 = pack4(q1.x, q1.y, q1.z, q1.w, qm);
            reinterpret_cast<int2*>(Ai8 + (size_t)row * D_DIM)[lane] = make_int2(p0, p1);
            if (lane == 0) {
                float qn = sqrtf(ssq), kn = sqrtf(ssk);
                float lp = dot / fmaxf(qn * kn, 1e-8f) * INV_T;
                fA[row]     = amx * (INV_T * LOG2E / 127.0f) / fmaxf(qn, 1e-8f);
                lpos[row]   = lp;
                rowsum[row] = __expf(lp);   // positive-logit term; inits accumulator
            }
        }
    } else {
        const int qb = blockIdx.x - 256;
#pragma unroll
        for (int rr = 0; rr < 8; ++rr) {
            const int row = (qb << 5) + (wave << 3) + rr;
            const float4* uv = reinterpret_cast<const float4*>(queue + (size_t)row * D_DIM) + lane * 2;
            float4 u0 = uv[0], u1 = uv[1];
            float ss = u0.x*u0.x + u0.y*u0.y + u0.z*u0.z + u0.w*u0.w
                     + u1.x*u1.x + u1.y*u1.y + u1.z*u1.z + u1.w*u1.w;
            float amx = fmaxf(fmaxf(fmaxf(fabsf(u0.x), fabsf(u0.y)),
                                    fmaxf(fabsf(u0.z), fabsf(u0.w))),
                              fmaxf(fmaxf(fabsf(u1.x), fabsf(u1.y)),
                                    fmaxf(fabsf(u1.z), fabsf(u1.w))));
#pragma unroll
            for (int off = 32; off > 0; off >>= 1) {
                ss  += __shfl_xor(ss, off, 64);
                amx = fmaxf(amx, __shfl_xor(amx, off, 64));
            }
            const float qm = 127.0f / amx;
            const int p0 = pack4(u0.x, u0.y, u0.z, u0.w, qm);
            const int p1 = pack4(u1.x, u1.y, u1.z, u1.w, qm);
            reinterpret_cast<int2*>(Bi8 + (size_t)row * D_DIM)[lane] = make_int2(p0, p1);
            if (lane == 0)
                fB[row] = amx * (1.0f / 127.0f) / fmaxf(sqrtf(ss), 1e-8f);
        }
    }
}

// ---------------------------------------------------------------------------
// Kernel 2: NT-GEMM (i8, K=64/instr) with fused exp-rowsum.
// Round-7: EXACT round-3 loop (best measured: 114us, 76 VGPR, (256,3) —
// the local optimum after 8-phase(-), counted-vmcnt(-), occ-4(- twice),
// j-outer slim(-)) + exp2f/LOG2E rider (validated absmax 0.0) + ONE new
// variable: XCD co-location swizzle.
//   Default x-fastest order spreads one colGroup's 16 rowBlocks across all
//   8 XCDs -> every XCD-L2 fetches the 256KB B-panel itself (FETCH 133MB =
//   4x Bi8; drain waits run at L3/HBM latency).  Remap flat id f so all 16
//   rowBlocks of a colGroup land on ONE XCD (assumes round-robin f%8->XCD):
//     r8=f&7, s=f>>3, colGroup=r8+8*(s>>4), rowBlock=s&15   (bijective,
//     2048%8==0).  15/16 of B-loads become L2 hits (~200cy vs ~600-900cy)
//   -> shorter per-iteration drain stalls.  Pure work permutation: risk is
//   null, not regression.  Discriminator: FETCH_SIZE 133 -> ~40-60MB.
// ---------------------------------------------------------------------------
__global__ __launch_bounds__(256, 3) void gemm_exp_kernel(
    const char* __restrict__ A, const char* __restrict__ B,
    const float* __restrict__ fA, const float* __restrict__ fB,
    float* __restrict__ rowsum) {
    __shared__ char sA[2 * 8192];
    __shared__ char sB[2 * 8192];
    const int tid  = threadIdx.x;
    const int wave = tid >> 6, lane = tid & 63;

    // XCD co-location swizzle (see header comment)
    const int f = blockIdx.y * 16 + blockIdx.x;   // flat id, x fastest
    const int r8 = f & 7, s = f >> 3;
    const int colGroup = r8 + 8 * (s >> 4);       // 0..127
    const int rowBlock = s & 15;                  // 0..15

    const int wm = wave >> 1, wn = wave & 1;
    const int q4 = lane >> 4, m16 = lane & 15;

    // staging lane map: lane = r4*4 + c2; LDS slot (r4,c2) <- global chunk
    // g = c2 ^ ((r4>>1)&3)  (source-address swizzle; dest is uniform+lane*16)
    const int r4 = lane >> 2, c2 = lane & 3;
    const int gsw = c2 ^ ((r4 >> 1) & 3);
    const int j0 = wave, j1 = wave + 4;          // 16-row chunks this wave stages
    const char* gA  = A + ((size_t)(rowBlock * 128 + r4)) * 512 + gsw * 16;
    const char* gB0 = B + ((size_t)(colGroup * NC * 128 + r4)) * 512 + gsw * 16;
    const int rsw = (q4 ^ ((m16 >> 1) & 3)) * 16;   // read-side swizzled byte offset

    // hoisted row dequant factors (same rows for every colBlock)
    float fAv[4][4];
#pragma unroll
    for (int i = 0; i < 4; ++i)
#pragma unroll
        for (int r = 0; r < 4; ++r)
            fAv[i][r] = fA[rowBlock * 128 + wm * 64 + i * 16 + q4 * 4 + r];

    float srow[4][4] = {{0.f,0.f,0.f,0.f},{0.f,0.f,0.f,0.f},
                        {0.f,0.f,0.f,0.f},{0.f,0.f,0.f,0.f}};
    i32x4 acc[4][4] = {};

    // stage(t, bufsel): issue 4 global_load_lds for iteration t
#define STAGE(T, BUF) do {                                                        \
        const int cb_ = (T) >> 3, kof_ = ((T) & 7) * 64;                          \
        const char* gBc_ = gB0 + ((size_t)cb_ << 16);                             \
        char* dA_ = &sA[(BUF) * 8192];                                            \
        char* dB_ = &sB[(BUF) * 8192];                                            \
        gload_lds16(gA   + (size_t)j0 * 16 * 512 + kof_, &dA_[j0 * 1024]);        \
        gload_lds16(gA   + (size_t)j1 * 16 * 512 + kof_, &dA_[j1 * 1024]);        \
        gload_lds16(gBc_ + (size_t)j0 * 16 * 512 + kof_, &dB_[j0 * 1024]);        \
        gload_lds16(gBc_ + (size_t)j1 * 16 * 512 + kof_, &dB_[j1 * 1024]);        \
    } while (0)

    STAGE(0, 0);

    for (int t = 0; t < NT; ++t) {
        const int cur = t & 1;
        __syncthreads();                  // drains loads(t) (one stage in flight)
        if (t + 1 < NT) STAGE(t + 1, cur ^ 1);

        const char* bA = &sA[cur * 8192];
        const char* bB = &sB[cur * 8192];
        i32x4 af[4], bq[4];
#pragma unroll
        for (int i = 0; i < 4; ++i)
            af[i] = *reinterpret_cast<const i32x4*>(&bA[(wm * 64 + i * 16 + m16) * 64 + rsw]);
#pragma unroll
        for (int j = 0; j < 4; ++j)
            bq[j] = *reinterpret_cast<const i32x4*>(&bB[(wn * 64 + j * 16 + m16) * 64 + rsw]);
#pragma unroll
        for (int i = 0; i < 4; ++i)
#pragma unroll
            for (int j = 0; j < 4; ++j)
                mfma_i8(acc[i][j], af[i], bq[j]);

        if ((t & 7) == 7) {               // colBlock done: exp-accumulate, reset acc
            const int colBlock = colGroup * NC + (t >> 3);
            float fBv[4];
#pragma unroll
            for (int j = 0; j < 4; ++j)
                fBv[j] = fB[colBlock * 128 + wn * 64 + j * 16 + m16];
#pragma unroll
            for (int i = 0; i < 4; ++i)
#pragma unroll
                for (int r = 0; r < 4; ++r) {
                    float s2 = 0.f;
#pragma unroll
                    for (int j = 0; j < 4; ++j)
                        s2 += __builtin_exp2f((float)acc[i][j][r] * fAv[i][r] * fBv[j]);
                    srow[i][r] += s2;
                    acc[i][0][r] = 0; acc[i][1][r] = 0;
                    acc[i][2][r] = 0; acc[i][3][r] = 0;
                }
        }
    }
#undef STAGE

    // one shuffle-reduce + atomic per row per block
#pragma unroll
    for (int i = 0; i < 4; ++i)
#pragma unroll
        for (int r = 0; r < 4; ++r) {
            float s2 = srow[i][r];
#pragma unroll
            for (int off = 1; off < 16; off <<= 1)
                s2 += __shfl_xor(s2, off, 64);
            if (m16 == 0) {
                const int grow = rowBlock * 128 + wm * 64 + i * 16 + q4 * 4 + r;
                atomicAdd(&rowsum[grow], s2);
            }
        }
}

// ---------------------------------------------------------------------------
// Kernel 3: loss = mean(log(rowsum) - lpos)
// ---------------------------------------------------------------------------
__global__ __launch_bounds__(256) void finalize_kernel(
    const float* __restrict__ rowsum, const float* __restrict__ lpos,
    float* __restrict__ out) {
    const int tid = threadIdx.x;
    float acc = 0.f;
    for (int n = tid; n < N_ROWS; n += 256)
        acc += __logf(rowsum[n]) - lpos[n];
#pragma unroll
    for (int off = 32; off > 0; off >>= 1) acc += __shfl_xor(acc, off, 64);
    __shared__ float red[4];
    if ((tid & 63) == 0) red[tid >> 6] = acc;
    __syncthreads();
    if (tid == 0) out[0] = (red[0] + red[1] + red[2] + red[3]) * (1.0f / (float)N_ROWS);
}

extern "C" void kernel_launch(void* const* d_in, const int* in_sizes, int n_in,
                              void* d_out, int out_size, void* d_ws, size_t ws_size,
                              hipStream_t stream) {
    const float* query = (const float*)d_in[0];
    const float* keys  = (const float*)d_in[1];
    const float* queue = (const float*)d_in[2];

    char* ws = (char*)d_ws;
    char*  Ai8 = ws;            ws += (size_t)N_ROWS * D_DIM;                 // 1 MB
    char*  Bi8 = ws;            ws += (size_t)K_NEG  * D_DIM;                 // 32 MB
    float* fA   = (float*)ws;   ws += (size_t)N_ROWS * sizeof(float);
    float* fB   = (float*)ws;   ws += (size_t)K_NEG  * sizeof(float);
    float* lpos = (float*)ws;   ws += (size_t)N_ROWS * sizeof(float);
    float* rsum = (float*)ws;   ws += (size_t)N_ROWS * sizeof(float);

    prep_all_kernel<<<2304, 256, 0, stream>>>(
        query, keys, queue, Ai8, Bi8, fA, fB, lpos, rsum);
    gemm_exp_kernel<<<dim3(N_ROWS / 128, K_NEG / 128 / NC), 256, 0, stream>>>(
        Ai8, Bi8, fA, fB, rsum);
    finalize_kernel<<<1, 256, 0, stream>>>(rsum, lpos, (float*)d_out);
}